// Round 14
// baseline (165.713 us; speedup 1.0000x reference)
//
#include <hip/hip_runtime.h>
#include <math.h>
#include <stdint.h>

#define NLEV 16
#define TBL 524288
#define TMASK (TBL - 1)
#define BLOCK 256
#define SPT 4            // samples per thread in encode
#define MSPT 2           // samples per thread in MLP
#define P1 2654435761u
#define P2 805459861u

struct ResArr { float r[NLEV]; };

typedef __attribute__((ext_vector_type(4))) float f32x4;
// 8B-aligned 16B load (table entries are float2-aligned; dwordx4 only needs dword align)
struct __attribute__((packed, aligned(8))) f4wrap { f32x4 v; };

__device__ __forceinline__ float silu_f(float v) {
    return __fdividef(v, 1.0f + __expf(-v));
}

// ---------------- Kernel A: hash-grid encode ----------------
// Phase-split level->XCD mapping (each XCD's L2 holds exactly one 4MB slice),
// corner pairing (dim0 hash coeff == 1 -> corners c,c+4 adjacent: one dwordx4
// covers both), SPT=4. Pinned ~105us: ~65K line-fills/CU at ~200-400cy L2-hit
// latency against the per-CU outstanding-request cap (r5 SPT2/68%occ == r6
// SPT4/34%occ confirmed saturation).
__global__ void __launch_bounds__(BLOCK)
encode_kernel(const float* __restrict__ x,
              const float* __restrict__ emb,
              float2* __restrict__ enc_ws,
              int nsamp, ResArr res)
{
    const int bid  = blockIdx.x;
    const int half = gridDim.x >> 1;
    int lvl, chunk;
    if (bid < half) { lvl = bid & 7;               chunk = bid >> 3; }
    else            { lvl = 8 + ((bid - half) & 7); chunk = (bid - half) >> 3; }

    const int t  = threadIdx.x;
    const int s0 = chunk * (BLOCK * SPT) + t;
    const float rs = res.r[lvl];
    const float* tabf = emb + (size_t)lvl * TBL * 2;   // float view of level slice

    uint32_t i0[SPT][4];
    float w0[SPT], w1[SPT], w2[SPT];
    uint32_t bad = 0;

    #pragma unroll
    for (int p = 0; p < SPT; ++p) {
        const int s = s0 + p * BLOCK;
        const float xv0 = __builtin_nontemporal_load(&x[(size_t)s * 3 + 0]);
        const float xv1 = __builtin_nontemporal_load(&x[(size_t)s * 3 + 1]);
        const float xv2 = __builtin_nontemporal_load(&x[(size_t)s * 3 + 2]);
        const float g0 = (xv0 + 1.0f) * 0.5f * rs;
        const float g1 = (xv1 + 1.0f) * 0.5f * rs;
        const float g2 = (xv2 + 1.0f) * 0.5f * rs;
        const float f0 = floorf(g0), f1 = floorf(g1), f2 = floorf(g2);
        w0[p] = g0 - f0; w1[p] = g1 - f1; w2[p] = g2 - f2;
        const uint32_t hb = (uint32_t)f0 + (uint32_t)f1 * P1 + (uint32_t)f2 * P2;
        #pragma unroll
        for (int q = 0; q < 4; ++q) {     // q: (dim1,dim2) corner bits; dim0 paired
            uint32_t h = hb;
            if ((q >> 1) & 1) h += P1;
            if (q & 1)        h += P2;
            i0[p][q] = h & TMASK;
            bad |= (uint32_t)(i0[p][q] == TMASK);
        }
    }

    f32x4 v[SPT][4];
    if (__builtin_expect(__any((int)bad), 0)) {
        // rare wrap path: second entry of a pair is index 0
        #pragma unroll
        for (int p = 0; p < SPT; ++p)
            #pragma unroll
            for (int q = 0; q < 4; ++q) {
                const uint32_t a = i0[p][q];
                const uint32_t b = (a + 1u) & TMASK;
                const float2 lo = *(const float2*)(tabf + 2 * (size_t)a);
                const float2 hi = *(const float2*)(tabf + 2 * (size_t)b);
                v[p][q] = f32x4{lo.x, lo.y, hi.x, hi.y};
            }
    } else {
        // fast path: all 16 pair-loads independent & in flight together
        #pragma unroll
        for (int p = 0; p < SPT; ++p)
            #pragma unroll
            for (int q = 0; q < 4; ++q)
                v[p][q] = ((const f4wrap*)(tabf + 2 * (size_t)i0[p][q]))->v;
    }

    #pragma unroll
    for (int p = 0; p < SPT; ++p) {
        const float om0 = 1.0f - w0[p], om1 = 1.0f - w1[p], om2 = 1.0f - w2[p];
        float e0 = 0.0f, e1 = 0.0f;
        #pragma unroll
        for (int q = 0; q < 4; ++q) {
            float wb = (((q >> 1) & 1) ? w1[p] : om1) * ((q & 1) ? w2[p] : om2);
            const float c0 = om0 * wb;          // corner with dim0 bit = 0
            const float c1 = w0[p] * wb;        // corner with dim0 bit = 1
            e0 = fmaf(c0, v[p][q].x, fmaf(c1, v[p][q].z, e0));
            e1 = fmaf(c0, v[p][q].y, fmaf(c1, v[p][q].w, e1));
        }
        const int s = s0 + p * BLOCK;
        union { float2 f; unsigned long long u; } pk;
        pk.f.x = e0; pk.f.y = e1;
        __builtin_nontemporal_store(pk.u,
            (unsigned long long*)&enc_ws[(size_t)lvl * nsamp + s]);
    }
}

// ---------------- Kernel B: MLP 32 -> 64 -> 64 -> 1 ----------------
// I$-streaming hypothesis test: r7..r13 all pipe mixes landed 52-59us; the
// common factor was the ~100KB fully-unrolled body (each wave STREAMS ~14K
// instructions through a 32KB I$ with zero reuse). This version = r7's
// all-LDS arithmetic (bit-identical) but with ROLLED i-loops: code ~2KB,
// I$-resident. hA/hB stay in registers (only k is unrolled); LDS addressing
// takes runtime i.
__global__ void __launch_bounds__(BLOCK, 2)
mlp_kernel(const float2* __restrict__ enc_ws,
           const float* __restrict__ W1,
           const float* __restrict__ b1,
           const float* __restrict__ W2,
           const float* __restrict__ b2,
           const float* __restrict__ Wout,
           const float* __restrict__ bout,
           float* __restrict__ out, int nsamp)
{
    __shared__ float sW1[64 * 32];
    __shared__ float sW2[64 * 64];
    __shared__ float sB1[64];
    __shared__ float sB2[64];
    __shared__ float sWo[64];
    __shared__ float sBo[1];

    const int t = threadIdx.x;

    // cooperative coalesced staging: W1 (512 float4) + W2 (1024 float4)
    {
        const float4* w1v = (const float4*)W1;
        float4* s1v = (float4*)sW1;
        #pragma unroll
        for (int i = 0; i < 2; ++i) s1v[t + i * BLOCK] = w1v[t + i * BLOCK];
        const float4* w2v = (const float4*)W2;
        float4* s2v = (float4*)sW2;
        #pragma unroll
        for (int i = 0; i < 4; ++i) s2v[t + i * BLOCK] = w2v[t + i * BLOCK];
        if (t < 64) {
            sB1[t] = b1[t];
            sB2[t] = b2[t];
            sWo[t] = Wout[t];
        }
        if (t == 0) sBo[0] = bout[0];
    }
    __syncthreads();

    const int sA = blockIdx.x * (BLOCK * MSPT) + t;
    const int sB = sA + BLOCK;

    float encA[2 * NLEV], encB[2 * NLEV];
    #pragma unroll
    for (int l = 0; l < NLEV; ++l) {
        union { unsigned long long u; float f[2]; } ua, ub;
        ua.u = *(const unsigned long long*)&enc_ws[(size_t)l * nsamp + sA];
        ub.u = *(const unsigned long long*)&enc_ws[(size_t)l * nsamp + sB];
        encA[2 * l] = ua.f[0]; encA[2 * l + 1] = ua.f[1];
        encB[2 * l] = ub.f[0]; encB[2 * l + 1] = ub.f[1];
    }

    // ---- layer 1: rolled i-loop, LDS broadcast weights ----
    float hA[64], hB[64];
    #pragma unroll 4
    for (int i = 0; i < 64; ++i) {
        const float bi = sB1[i];
        float a = bi, b = bi;
        #pragma unroll
        for (int k = 0; k < 32; k += 4) {
            const float4 w = *(const float4*)&sW1[i * 32 + k];  // ds_read_b128 broadcast
            a = fmaf(encA[k],     w.x, a); b = fmaf(encB[k],     w.x, b);
            a = fmaf(encA[k + 1], w.y, a); b = fmaf(encB[k + 1], w.y, b);
            a = fmaf(encA[k + 2], w.z, a); b = fmaf(encB[k + 2], w.z, b);
            a = fmaf(encA[k + 3], w.w, a); b = fmaf(encB[k + 3], w.w, b);
        }
        hA[i] = silu_f(a);
        hB[i] = silu_f(b);
    }

    // ---- layers 2+3: rolled i-loop ----
    float oA = sBo[0], oB = sBo[0];
    #pragma unroll 2
    for (int i = 0; i < 64; ++i) {
        const float bi = sB2[i];
        float a = bi, b = bi;
        #pragma unroll
        for (int k = 0; k < 64; k += 4) {
            const float4 w = *(const float4*)&sW2[i * 64 + k];
            a = fmaf(hA[k],     w.x, a); b = fmaf(hB[k],     w.x, b);
            a = fmaf(hA[k + 1], w.y, a); b = fmaf(hB[k + 1], w.y, b);
            a = fmaf(hA[k + 2], w.z, a); b = fmaf(hB[k + 2], w.z, b);
            a = fmaf(hA[k + 3], w.w, a); b = fmaf(hB[k + 3], w.w, b);
        }
        const float wo = sWo[i];
        oA = fmaf(silu_f(a), wo, oA);
        oB = fmaf(silu_f(b), wo, oB);
    }

    out[sA] = oA;
    out[sB] = oB;
}

// ---------------- Fallback: monolithic (if ws too small) ----------------
__global__ void __launch_bounds__(BLOCK)
hashgrid_mlp_kernel(const float* __restrict__ x,
                    const float* __restrict__ emb,
                    const float* __restrict__ W1,
                    const float* __restrict__ b1,
                    const float* __restrict__ W2,
                    const float* __restrict__ b2,
                    const float* __restrict__ Wout,
                    const float* __restrict__ bout,
                    float* __restrict__ out,
                    ResArr res)
{
    const int t = threadIdx.x;
    const int s = blockIdx.x * BLOCK + t;

    const float xn0 = (x[(size_t)s * 3 + 0] + 1.0f) * 0.5f;
    const float xn1 = (x[(size_t)s * 3 + 1] + 1.0f) * 0.5f;
    const float xn2 = (x[(size_t)s * 3 + 2] + 1.0f) * 0.5f;

    float enc[2 * NLEV];
    #pragma unroll
    for (int l = 0; l < NLEV; ++l) {
        const float rs = res.r[l];
        const float g0 = xn0 * rs, g1 = xn1 * rs, g2 = xn2 * rs;
        const float f0 = floorf(g0), f1 = floorf(g1), f2 = floorf(g2);
        const float w0 = g0 - f0, w1 = g1 - f1, w2 = g2 - f2;
        const uint32_t hb = (uint32_t)f0 + (uint32_t)f1 * P1 + (uint32_t)f2 * P2;
        const float2* tab = (const float2*)emb + (size_t)l * TBL;
        const float om0 = 1.0f - w0, om1 = 1.0f - w1, om2 = 1.0f - w2;
        float e0 = 0.0f, e1 = 0.0f;
        #pragma unroll
        for (int c = 0; c < 8; ++c) {
            const uint32_t cb0 = (c >> 2) & 1, cb1 = (c >> 1) & 1, cb2 = c & 1;
            uint32_t h = hb;
            if (cb0) h += 1u;
            if (cb1) h += P1;
            if (cb2) h += P2;
            h &= TMASK;
            const float2 vv = tab[h];
            float wt = (cb0 ? w0 : om0) * (cb1 ? w1 : om1);
            wt *= (cb2 ? w2 : om2);
            e0 = fmaf(wt, vv.x, e0);
            e1 = fmaf(wt, vv.y, e1);
        }
        enc[2 * l + 0] = e0;
        enc[2 * l + 1] = e1;
    }

    float h1[64];
    #pragma unroll
    for (int i = 0; i < 64; ++i) {
        float acc = b1[i];
        #pragma unroll
        for (int k = 0; k < 32; ++k)
            acc = fmaf(enc[k], W1[i * 32 + k], acc);
        h1[i] = silu_f(acc);
    }
    float o = bout[0];
    #pragma unroll
    for (int i = 0; i < 64; ++i) {
        float acc = b2[i];
        #pragma unroll
        for (int k = 0; k < 64; ++k)
            acc = fmaf(h1[k], W2[i * 64 + k], acc);
        o = fmaf(silu_f(acc), Wout[i], o);
    }
    out[s] = o;
}

extern "C" void kernel_launch(void* const* d_in, const int* in_sizes, int n_in,
                              void* d_out, int out_size, void* d_ws, size_t ws_size,
                              hipStream_t stream) {
    const float* x    = (const float*)d_in[0];
    const float* emb  = (const float*)d_in[1];
    const float* W1   = (const float*)d_in[2];
    const float* b1   = (const float*)d_in[3];
    const float* W2   = (const float*)d_in[4];
    const float* b2   = (const float*)d_in[5];
    const float* Wout = (const float*)d_in[6];
    const float* bout = (const float*)d_in[7];
    float* out = (float*)d_out;

    ResArr res;
    const double lg0 = log(16.0), lg1 = log(2048.0);
    for (int i = 0; i < NLEV; ++i)
        res.r[i] = (float)exp(lg0 + (lg1 - lg0) * (double)i / 15.0);

    const int n = in_sizes[0] / 3;                     // 262144 samples
    const size_t ws_needed = (size_t)n * NLEV * sizeof(float2);

    if (ws_size >= ws_needed) {
        float2* enc_ws = (float2*)d_ws;
        const int chunks = n / (BLOCK * SPT);          // 256
        dim3 gridA(2 * 8 * chunks);                    // 4096 blocks, phase-split
        encode_kernel<<<gridA, BLOCK, 0, stream>>>(x, emb, enc_ws, n, res);
        dim3 gridB(n / (BLOCK * MSPT));                // 512 blocks
        mlp_kernel<<<gridB, BLOCK, 0, stream>>>(enc_ws, W1, b1, W2, b2,
                                                Wout, bout, out, n);
    } else {
        dim3 grid(n / BLOCK);
        hashgrid_mlp_kernel<<<grid, BLOCK, 0, stream>>>(x, emb, W1, b1, W2, b2,
                                                        Wout, bout, out, res);
    }
}

// Round 15
// 137.759 us; speedup vs baseline: 1.2029x; 1.2029x over previous
//
#include <hip/hip_runtime.h>
#include <math.h>
#include <stdint.h>

#define NLEV 16
#define TBL 524288
#define TMASK (TBL - 1)
#define BLOCK 256
#define SPT 4            // samples per thread in encode
#define P1 2654435761u
#define P2 805459861u

struct ResArr { float r[NLEV]; };

typedef __attribute__((ext_vector_type(4))) float f32x4;
typedef __attribute__((ext_vector_type(8))) short bf16x8;   // 8 bf16 = 4 VGPRs
// 8B-aligned 16B load (table entries are float2-aligned)
struct __attribute__((packed, aligned(8))) f4wrap { f32x4 v; };

__device__ __forceinline__ float silu_f(float v) {
    return __fdividef(v, 1.0f + __expf(-v));
}

// fp32 -> bf16 bits (RNE)
__device__ __forceinline__ uint32_t f2bf(float f) {
    uint32_t u = __float_as_uint(f);
    return (u + 0x7FFFu + ((u >> 16) & 1u)) >> 16;
}
__device__ __forceinline__ float bf2f(uint32_t b) {
    return __uint_as_float(b << 16);
}
// split x = hi + lo (both bf16); write element e of the two fragments
__device__ __forceinline__ void split_bf(float x, bf16x8& hi, bf16x8& lo, int e) {
    const uint32_t hb = f2bf(x);
    hi[e] = (short)hb;
    lo[e] = (short)f2bf(x - bf2f(hb));
}

// ---------------- Kernel A: hash-grid encode (unchanged, ~105us) ----------------
// Phase-split level->XCD mapping; corner pairing via dwordx4; SPT=4.
// Pinned by per-CU outstanding-gather (MSHR) cap at ~200-400cy L2 latency.
__global__ void __launch_bounds__(BLOCK)
encode_kernel(const float* __restrict__ x,
              const float* __restrict__ emb,
              float2* __restrict__ enc_ws,
              int nsamp, ResArr res)
{
    const int bid  = blockIdx.x;
    const int half = gridDim.x >> 1;
    int lvl, chunk;
    if (bid < half) { lvl = bid & 7;               chunk = bid >> 3; }
    else            { lvl = 8 + ((bid - half) & 7); chunk = (bid - half) >> 3; }

    const int t  = threadIdx.x;
    const int s0 = chunk * (BLOCK * SPT) + t;
    const float rs = res.r[lvl];
    const float* tabf = emb + (size_t)lvl * TBL * 2;

    uint32_t i0[SPT][4];
    float w0[SPT], w1[SPT], w2[SPT];
    uint32_t bad = 0;

    #pragma unroll
    for (int p = 0; p < SPT; ++p) {
        const int s = s0 + p * BLOCK;
        const float xv0 = __builtin_nontemporal_load(&x[(size_t)s * 3 + 0]);
        const float xv1 = __builtin_nontemporal_load(&x[(size_t)s * 3 + 1]);
        const float xv2 = __builtin_nontemporal_load(&x[(size_t)s * 3 + 2]);
        const float g0 = (xv0 + 1.0f) * 0.5f * rs;
        const float g1 = (xv1 + 1.0f) * 0.5f * rs;
        const float g2 = (xv2 + 1.0f) * 0.5f * rs;
        const float f0 = floorf(g0), f1 = floorf(g1), f2 = floorf(g2);
        w0[p] = g0 - f0; w1[p] = g1 - f1; w2[p] = g2 - f2;
        const uint32_t hb = (uint32_t)f0 + (uint32_t)f1 * P1 + (uint32_t)f2 * P2;
        #pragma unroll
        for (int q = 0; q < 4; ++q) {
            uint32_t h = hb;
            if ((q >> 1) & 1) h += P1;
            if (q & 1)        h += P2;
            i0[p][q] = h & TMASK;
            bad |= (uint32_t)(i0[p][q] == TMASK);
        }
    }

    f32x4 v[SPT][4];
    if (__builtin_expect(__any((int)bad), 0)) {
        #pragma unroll
        for (int p = 0; p < SPT; ++p)
            #pragma unroll
            for (int q = 0; q < 4; ++q) {
                const uint32_t a = i0[p][q];
                const uint32_t b = (a + 1u) & TMASK;
                const float2 lo = *(const float2*)(tabf + 2 * (size_t)a);
                const float2 hi = *(const float2*)(tabf + 2 * (size_t)b);
                v[p][q] = f32x4{lo.x, lo.y, hi.x, hi.y};
            }
    } else {
        #pragma unroll
        for (int p = 0; p < SPT; ++p)
            #pragma unroll
            for (int q = 0; q < 4; ++q)
                v[p][q] = ((const f4wrap*)(tabf + 2 * (size_t)i0[p][q]))->v;
    }

    #pragma unroll
    for (int p = 0; p < SPT; ++p) {
        const float om0 = 1.0f - w0[p], om1 = 1.0f - w1[p], om2 = 1.0f - w2[p];
        float e0 = 0.0f, e1 = 0.0f;
        #pragma unroll
        for (int q = 0; q < 4; ++q) {
            float wb = (((q >> 1) & 1) ? w1[p] : om1) * ((q & 1) ? w2[p] : om2);
            const float c0 = om0 * wb;
            const float c1 = w0[p] * wb;
            e0 = fmaf(c0, v[p][q].x, fmaf(c1, v[p][q].z, e0));
            e1 = fmaf(c0, v[p][q].y, fmaf(c1, v[p][q].w, e1));
        }
        const int s = s0 + p * BLOCK;
        union { float2 f; unsigned long long u; } pk;
        pk.f.x = e0; pk.f.y = e1;
        __builtin_nontemporal_store(pk.u,
            (unsigned long long*)&enc_ws[(size_t)lvl * nsamp + s]);
    }
}

// ---------------- Kernel B: MLP via split-bf16 MFMA ----------------
// One wave = 32 samples (2 M-tiles of 16). Weight fragments are read ONCE per
// wave and amortized over the 16-sample tile dim (kills the r7-r14 broadcast
// bottleneck: DS demand drops ~25x, weights feed the idle matrix pipe).
// Precision: x = hi + lo bf16 (RNE); A*B = Ahi*Bhi + Ahi*Blo + Alo*Bhi
// (~2^-17 rel per product). K-slot packing is self-consistent between A and B
// so the HW's internal slot->k convention cancels out.
// Verified C/D layout: col = lane&15, row = (lane>>4)*4 + reg.
__global__ void __launch_bounds__(BLOCK)
mlp_mfma_kernel(const float2* __restrict__ enc_ws,
                const float* __restrict__ W1,
                const float* __restrict__ b1,
                const float* __restrict__ W2,
                const float* __restrict__ b2,
                const float* __restrict__ Wout,
                const float* __restrict__ bout,
                float* __restrict__ out, int nsamp)
{
    __shared__ __align__(16) float hbuf[4][32 * 68];   // per-wave h tile, padded (+4) rows

    const int tid  = threadIdx.x;
    const int wid  = tid >> 6;
    const int lane = tid & 63;
    const int l15  = lane & 15;
    const int g    = lane >> 4;                         // k-group 0..3
    const int sbase = blockIdx.x * 128 + wid * 32;
    float* hw = hbuf[wid];

    // ---- B1 fragments (B = W1^T: B[k][j] = W1[j][k]); col j = n*16+l15 ----
    bf16x8 b1hi[4], b1lo[4];
    float  b1v[4];
    #pragma unroll
    for (int n = 0; n < 4; ++n) {
        const float* wr = W1 + (n * 16 + l15) * 32 + g * 8;
        const f32x4 wv0 = ((const f4wrap*)wr)->v;
        const f32x4 wv1 = ((const f4wrap*)(wr + 4))->v;
        #pragma unroll
        for (int e = 0; e < 4; ++e) {
            split_bf(wv0[e], b1hi[n], b1lo[n], e);
            split_bf(wv1[e], b1hi[n], b1lo[n], e + 4);
        }
        b1v[n] = b1[n * 16 + l15];
    }

    // ---- layer 1: D1 = enc * W1^T, 2 M-tiles ----
    #pragma unroll
    for (int m = 0; m < 2; ++m) {
        // A fragment: row = sample l15 of tile, k = g*8+e -> levels g*4+d
        bf16x8 ahi, alo;
        const int s = sbase + m * 16 + l15;
        #pragma unroll
        for (int d = 0; d < 4; ++d) {
            union { unsigned long long u; float f[2]; } uv;
            uv.u = *(const unsigned long long*)&enc_ws[(size_t)(g * 4 + d) * nsamp + s];
            split_bf(uv.f[0], ahi, alo, 2 * d);
            split_bf(uv.f[1], ahi, alo, 2 * d + 1);
        }
        #pragma unroll
        for (int n = 0; n < 4; ++n) {
            f32x4 acc = {0.f, 0.f, 0.f, 0.f};
            acc = __builtin_amdgcn_mfma_f32_16x16x32_bf16(alo, b1hi[n], acc, 0, 0, 0);
            acc = __builtin_amdgcn_mfma_f32_16x16x32_bf16(ahi, b1lo[n], acc, 0, 0, 0);
            acc = __builtin_amdgcn_mfma_f32_16x16x32_bf16(ahi, b1hi[n], acc, 0, 0, 0);
            // D layout: row (sample) = g*4+r, col (hidden) = l15
            #pragma unroll
            for (int r = 0; r < 4; ++r) {
                const int row = m * 16 + g * 4 + r;
                const int col = n * 16 + l15;
                hw[row * 68 + col] = silu_f(acc[r] + b1v[n]);
            }
        }
    }

    // ---- layer 2: D2 = h * W2^T, K=64 as two 32-steps ----
    f32x4 acc2[2][4];
    #pragma unroll
    for (int m = 0; m < 2; ++m)
        #pragma unroll
        for (int n = 0; n < 4; ++n)
            acc2[m][n] = f32x4{0.f, 0.f, 0.f, 0.f};

    #pragma unroll
    for (int ks = 0; ks < 2; ++ks) {
        bf16x8 b2hi[4], b2lo[4];
        #pragma unroll
        for (int n = 0; n < 4; ++n) {
            const float* wr = W2 + (n * 16 + l15) * 64 + ks * 32 + g * 8;
            const f32x4 wv0 = ((const f4wrap*)wr)->v;
            const f32x4 wv1 = ((const f4wrap*)(wr + 4))->v;
            #pragma unroll
            for (int e = 0; e < 4; ++e) {
                split_bf(wv0[e], b2hi[n], b2lo[n], e);
                split_bf(wv1[e], b2hi[n], b2lo[n], e + 4);
            }
        }
        #pragma unroll
        for (int m = 0; m < 2; ++m) {
            bf16x8 ahi, alo;
            const float* hr = &hw[(m * 16 + l15) * 68 + ks * 32 + g * 8];
            const f32x4 h0 = *(const f32x4*)hr;
            const f32x4 h1 = *(const f32x4*)(hr + 4);
            #pragma unroll
            for (int e = 0; e < 4; ++e) {
                split_bf(h0[e], ahi, alo, e);
                split_bf(h1[e], ahi, alo, e + 4);
            }
            #pragma unroll
            for (int n = 0; n < 4; ++n) {
                acc2[m][n] = __builtin_amdgcn_mfma_f32_16x16x32_bf16(alo, b2hi[n], acc2[m][n], 0, 0, 0);
                acc2[m][n] = __builtin_amdgcn_mfma_f32_16x16x32_bf16(ahi, b2lo[n], acc2[m][n], 0, 0, 0);
                acc2[m][n] = __builtin_amdgcn_mfma_f32_16x16x32_bf16(ahi, b2hi[n], acc2[m][n], 0, 0, 0);
            }
        }
    }

    // ---- layer 3: out = bout + sum_j silu(h2[j]) * Wout[j] ----
    float b2v[4], wov[4];
    #pragma unroll
    for (int n = 0; n < 4; ++n) {
        b2v[n] = b2[n * 16 + l15];
        wov[n] = Wout[n * 16 + l15];
    }
    const float bo = bout[0];

    #pragma unroll
    for (int m = 0; m < 2; ++m) {
        float part[4] = {0.f, 0.f, 0.f, 0.f};
        #pragma unroll
        for (int n = 0; n < 4; ++n)
            #pragma unroll
            for (int r = 0; r < 4; ++r)
                part[r] += silu_f(acc2[m][n][r] + b2v[n]) * wov[n];
        // reduce across the 16-lane col group (l15 varies, g*4+r = sample row)
        #pragma unroll
        for (int mask = 1; mask <= 8; mask <<= 1)
            #pragma unroll
            for (int r = 0; r < 4; ++r)
                part[r] += __shfl_xor(part[r], mask, 64);
        if (l15 == 0) {
            #pragma unroll
            for (int r = 0; r < 4; ++r)
                out[sbase + m * 16 + g * 4 + r] = part[r] + bo;
        }
    }
}

// ---------------- Fallback: monolithic (if ws too small) ----------------
__global__ void __launch_bounds__(BLOCK)
hashgrid_mlp_kernel(const float* __restrict__ x,
                    const float* __restrict__ emb,
                    const float* __restrict__ W1,
                    const float* __restrict__ b1,
                    const float* __restrict__ W2,
                    const float* __restrict__ b2,
                    const float* __restrict__ Wout,
                    const float* __restrict__ bout,
                    float* __restrict__ out,
                    ResArr res)
{
    const int t = threadIdx.x;
    const int s = blockIdx.x * BLOCK + t;

    const float xn0 = (x[(size_t)s * 3 + 0] + 1.0f) * 0.5f;
    const float xn1 = (x[(size_t)s * 3 + 1] + 1.0f) * 0.5f;
    const float xn2 = (x[(size_t)s * 3 + 2] + 1.0f) * 0.5f;

    float enc[2 * NLEV];
    #pragma unroll
    for (int l = 0; l < NLEV; ++l) {
        const float rs = res.r[l];
        const float g0 = xn0 * rs, g1 = xn1 * rs, g2 = xn2 * rs;
        const float f0 = floorf(g0), f1 = floorf(g1), f2 = floorf(g2);
        const float w0 = g0 - f0, w1 = g1 - f1, w2 = g2 - f2;
        const uint32_t hb = (uint32_t)f0 + (uint32_t)f1 * P1 + (uint32_t)f2 * P2;
        const float2* tab = (const float2*)emb + (size_t)l * TBL;
        const float om0 = 1.0f - w0, om1 = 1.0f - w1, om2 = 1.0f - w2;
        float e0 = 0.0f, e1 = 0.0f;
        #pragma unroll
        for (int c = 0; c < 8; ++c) {
            const uint32_t cb0 = (c >> 2) & 1, cb1 = (c >> 1) & 1, cb2 = c & 1;
            uint32_t h = hb;
            if (cb0) h += 1u;
            if (cb1) h += P1;
            if (cb2) h += P2;
            h &= TMASK;
            const float2 vv = tab[h];
            float wt = (cb0 ? w0 : om0) * (cb1 ? w1 : om1);
            wt *= (cb2 ? w2 : om2);
            e0 = fmaf(wt, vv.x, e0);
            e1 = fmaf(wt, vv.y, e1);
        }
        enc[2 * l + 0] = e0;
        enc[2 * l + 1] = e1;
    }

    float h1[64];
    #pragma unroll
    for (int i = 0; i < 64; ++i) {
        float acc = b1[i];
        #pragma unroll
        for (int k = 0; k < 32; ++k)
            acc = fmaf(enc[k], W1[i * 32 + k], acc);
        h1[i] = silu_f(acc);
    }
    float o = bout[0];
    #pragma unroll
    for (int i = 0; i < 64; ++i) {
        float acc = b2[i];
        #pragma unroll
        for (int k = 0; k < 64; ++k)
            acc = fmaf(h1[k], W2[i * 64 + k], acc);
        o = fmaf(silu_f(acc), Wout[i], o);
    }
    out[s] = o;
}

extern "C" void kernel_launch(void* const* d_in, const int* in_sizes, int n_in,
                              void* d_out, int out_size, void* d_ws, size_t ws_size,
                              hipStream_t stream) {
    const float* x    = (const float*)d_in[0];
    const float* emb  = (const float*)d_in[1];
    const float* W1   = (const float*)d_in[2];
    const float* b1   = (const float*)d_in[3];
    const float* W2   = (const float*)d_in[4];
    const float* b2   = (const float*)d_in[5];
    const float* Wout = (const float*)d_in[6];
    const float* bout = (const float*)d_in[7];
    float* out = (float*)d_out;

    ResArr res;
    const double lg0 = log(16.0), lg1 = log(2048.0);
    for (int i = 0; i < NLEV; ++i)
        res.r[i] = (float)exp(lg0 + (lg1 - lg0) * (double)i / 15.0);

    const int n = in_sizes[0] / 3;                     // 262144 samples
    const size_t ws_needed = (size_t)n * NLEV * sizeof(float2);

    if (ws_size >= ws_needed) {
        float2* enc_ws = (float2*)d_ws;
        const int chunks = n / (BLOCK * SPT);          // 256
        dim3 gridA(2 * 8 * chunks);                    // 4096 blocks, phase-split
        encode_kernel<<<gridA, BLOCK, 0, stream>>>(x, emb, enc_ws, n, res);
        dim3 gridB(n / 128);                           // 2048 blocks, 128 samples each
        mlp_mfma_kernel<<<gridB, BLOCK, 0, stream>>>(enc_ws, W1, b1, W2, b2,
                                                     Wout, bout, out, n);
    } else {
        dim3 grid(n / BLOCK);
        hashgrid_mlp_kernel<<<grid, BLOCK, 0, stream>>>(x, emb, W1, b1, W2, b2,
                                                        Wout, bout, out, res);
    }
}

// Round 16
// 131.883 us; speedup vs baseline: 1.2565x; 1.0446x over previous
//
#include <hip/hip_runtime.h>
#include <math.h>
#include <stdint.h>

#define NLEV 16
#define TBL 524288
#define TMASK (TBL - 1)
#define BLOCK 256
#define SPT 4            // samples per thread in encode
#define P1 2654435761u
#define P2 805459861u

struct ResArr { float r[NLEV]; };

typedef __attribute__((ext_vector_type(4))) float f32x4;
typedef __attribute__((ext_vector_type(8))) short bf16x8;   // 8 bf16 = 4 VGPRs
struct __attribute__((packed, aligned(8))) f4wrap { f32x4 v; };

__device__ __forceinline__ float silu_f(float v) {
    return __fdividef(v, 1.0f + __expf(-v));
}

// fp32 -> bf16 bits (RNE)
__device__ __forceinline__ uint32_t f2bf(float f) {
    uint32_t u = __float_as_uint(f);
    return (u + 0x7FFFu + ((u >> 16) & 1u)) >> 16;
}
__device__ __forceinline__ float bf2f(uint32_t b) {
    return __uint_as_float(b << 16);
}
// split x = hi + lo (both bf16) for WEIGHT fragments (B-side keeps precision)
__device__ __forceinline__ void split_bf(float x, bf16x8& hi, bf16x8& lo, int e) {
    const uint32_t hb = f2bf(x);
    hi[e] = (short)hb;
    lo[e] = (short)f2bf(x - bf2f(hb));
}

// ---------------- Kernel A: hash-grid encode ----------------
// Phase-split level->XCD mapping; corner pairing via dwordx4; SPT=4. Pinned
// ~105us by per-CU outstanding-gather capacity (r5 SPT2/68%occ == r6
// SPT4/34%occ, both ~176 in-flight). NEW: emits bf16 pair (e0|e1<<16, 4B) —
// the fp32->bf16 cost rides free on this latency-bound kernel, write traffic
// halves, and the MLP's A-fragments become raw loaded dwords (zero VALU).
// enc error ~2^-9 rel of ~1e-4-scale values -> ~2e-7 at output (negligible).
__global__ void __launch_bounds__(BLOCK)
encode_kernel(const float* __restrict__ x,
              const float* __restrict__ emb,
              uint32_t* __restrict__ enc_ws,
              int nsamp, ResArr res)
{
    const int bid  = blockIdx.x;
    const int half = gridDim.x >> 1;
    int lvl, chunk;
    if (bid < half) { lvl = bid & 7;               chunk = bid >> 3; }
    else            { lvl = 8 + ((bid - half) & 7); chunk = (bid - half) >> 3; }

    const int t  = threadIdx.x;
    const int s0 = chunk * (BLOCK * SPT) + t;
    const float rs = res.r[lvl];
    const float* tabf = emb + (size_t)lvl * TBL * 2;

    uint32_t i0[SPT][4];
    float w0[SPT], w1[SPT], w2[SPT];
    uint32_t bad = 0;

    #pragma unroll
    for (int p = 0; p < SPT; ++p) {
        const int s = s0 + p * BLOCK;
        const float xv0 = __builtin_nontemporal_load(&x[(size_t)s * 3 + 0]);
        const float xv1 = __builtin_nontemporal_load(&x[(size_t)s * 3 + 1]);
        const float xv2 = __builtin_nontemporal_load(&x[(size_t)s * 3 + 2]);
        const float g0 = (xv0 + 1.0f) * 0.5f * rs;
        const float g1 = (xv1 + 1.0f) * 0.5f * rs;
        const float g2 = (xv2 + 1.0f) * 0.5f * rs;
        const float f0 = floorf(g0), f1 = floorf(g1), f2 = floorf(g2);
        w0[p] = g0 - f0; w1[p] = g1 - f1; w2[p] = g2 - f2;
        const uint32_t hb = (uint32_t)f0 + (uint32_t)f1 * P1 + (uint32_t)f2 * P2;
        #pragma unroll
        for (int q = 0; q < 4; ++q) {
            uint32_t h = hb;
            if ((q >> 1) & 1) h += P1;
            if (q & 1)        h += P2;
            i0[p][q] = h & TMASK;
            bad |= (uint32_t)(i0[p][q] == TMASK);
        }
    }

    f32x4 v[SPT][4];
    if (__builtin_expect(__any((int)bad), 0)) {
        #pragma unroll
        for (int p = 0; p < SPT; ++p)
            #pragma unroll
            for (int q = 0; q < 4; ++q) {
                const uint32_t a = i0[p][q];
                const uint32_t b = (a + 1u) & TMASK;
                const float2 lo = *(const float2*)(tabf + 2 * (size_t)a);
                const float2 hi = *(const float2*)(tabf + 2 * (size_t)b);
                v[p][q] = f32x4{lo.x, lo.y, hi.x, hi.y};
            }
    } else {
        #pragma unroll
        for (int p = 0; p < SPT; ++p)
            #pragma unroll
            for (int q = 0; q < 4; ++q)
                v[p][q] = ((const f4wrap*)(tabf + 2 * (size_t)i0[p][q]))->v;
    }

    #pragma unroll
    for (int p = 0; p < SPT; ++p) {
        const float om0 = 1.0f - w0[p], om1 = 1.0f - w1[p], om2 = 1.0f - w2[p];
        float e0 = 0.0f, e1 = 0.0f;
        #pragma unroll
        for (int q = 0; q < 4; ++q) {
            float wb = (((q >> 1) & 1) ? w1[p] : om1) * ((q & 1) ? w2[p] : om2);
            const float c0 = om0 * wb;
            const float c1 = w0[p] * wb;
            e0 = fmaf(c0, v[p][q].x, fmaf(c1, v[p][q].z, e0));
            e1 = fmaf(c0, v[p][q].y, fmaf(c1, v[p][q].w, e1));
        }
        const int s = s0 + p * BLOCK;
        const uint32_t pk = f2bf(e0) | (f2bf(e1) << 16);
        __builtin_nontemporal_store(pk, &enc_ws[(size_t)lvl * nsamp + s]);
    }
}

// ---------------- Kernel B: MLP via bf16-A / split-bf16-B MFMA ----------------
// A-side plain bf16 (enc pre-converted by encode; h rounded once) — error
// ~3e-6 at output, vs 3.5e-5 threshold headroom. B-side (weights) split
// hi+lo: 2 MFMAs per product. Per-sample split VALU: ZERO (r15's dominant
// cost). Weight fragments read once per wave, amortized over 16-sample tiles.
// C/D layout (HW-verified): col = lane&15, row = (lane>>4)*4 + reg.
__global__ void __launch_bounds__(BLOCK)
mlp_mfma_kernel(const uint32_t* __restrict__ enc_ws,
                const float* __restrict__ W1,
                const float* __restrict__ b1,
                const float* __restrict__ W2,
                const float* __restrict__ b2,
                const float* __restrict__ Wout,
                const float* __restrict__ bout,
                float* __restrict__ out, int nsamp)
{
    // per-wave h tile as bf16, rows padded to 72 shorts (144B: 4-bank row skew)
    __shared__ __align__(16) unsigned short hbuf[4][32 * 72];

    const int tid  = threadIdx.x;
    const int wid  = tid >> 6;
    const int lane = tid & 63;
    const int l15  = lane & 15;
    const int g    = lane >> 4;                         // k-group 0..3
    const int sbase = blockIdx.x * 128 + wid * 32;
    unsigned short* hw = hbuf[wid];

    // ---- B1 fragments (B[k][j] = W1[j][k], col j = n*16+l15), split hi/lo ----
    bf16x8 b1hi[4], b1lo[4];
    float  b1v[4];
    #pragma unroll
    for (int n = 0; n < 4; ++n) {
        const float* wr = W1 + (n * 16 + l15) * 32 + g * 8;
        const f32x4 wv0 = ((const f4wrap*)wr)->v;
        const f32x4 wv1 = ((const f4wrap*)(wr + 4))->v;
        #pragma unroll
        for (int e = 0; e < 4; ++e) {
            split_bf(wv0[e], b1hi[n], b1lo[n], e);
            split_bf(wv1[e], b1hi[n], b1lo[n], e + 4);
        }
        b1v[n] = b1[n * 16 + l15];
    }

    // ---- layer 1: A = 4 raw dwords (level g*4+d -> elements 2d,2d+1) ----
    #pragma unroll
    for (int m = 0; m < 2; ++m) {
        union { uint32_t u[4]; bf16x8 v; } af;
        const int s = sbase + m * 16 + l15;
        #pragma unroll
        for (int d = 0; d < 4; ++d)
            af.u[d] = enc_ws[(size_t)(g * 4 + d) * nsamp + s];
        #pragma unroll
        for (int n = 0; n < 4; ++n) {
            f32x4 acc = {0.f, 0.f, 0.f, 0.f};
            acc = __builtin_amdgcn_mfma_f32_16x16x32_bf16(af.v, b1lo[n], acc, 0, 0, 0);
            acc = __builtin_amdgcn_mfma_f32_16x16x32_bf16(af.v, b1hi[n], acc, 0, 0, 0);
            #pragma unroll
            for (int r = 0; r < 4; ++r) {
                const int row = m * 16 + g * 4 + r;
                const int col = n * 16 + l15;
                hw[row * 72 + col] = (unsigned short)f2bf(silu_f(acc[r] + b1v[n]));
            }
        }
    }
    // per-wave private tile + in-order wave DS ops: no barrier needed (r15-proven)

    // ---- layer 2: A = raw ds_read_b128 of 8 bf16; B2 split hi/lo ----
    f32x4 acc2[2][4];
    #pragma unroll
    for (int m = 0; m < 2; ++m)
        #pragma unroll
        for (int n = 0; n < 4; ++n)
            acc2[m][n] = f32x4{0.f, 0.f, 0.f, 0.f};

    #pragma unroll
    for (int ks = 0; ks < 2; ++ks) {
        bf16x8 b2hi[4], b2lo[4];
        #pragma unroll
        for (int n = 0; n < 4; ++n) {
            const float* wr = W2 + (n * 16 + l15) * 64 + ks * 32 + g * 8;
            const f32x4 wv0 = ((const f4wrap*)wr)->v;
            const f32x4 wv1 = ((const f4wrap*)(wr + 4))->v;
            #pragma unroll
            for (int e = 0; e < 4; ++e) {
                split_bf(wv0[e], b2hi[n], b2lo[n], e);
                split_bf(wv1[e], b2hi[n], b2lo[n], e + 4);
            }
        }
        #pragma unroll
        for (int m = 0; m < 2; ++m) {
            const bf16x8 a2 = *(const bf16x8*)&hw[(m * 16 + l15) * 72 + ks * 32 + g * 8];
            #pragma unroll
            for (int n = 0; n < 4; ++n) {
                acc2[m][n] = __builtin_amdgcn_mfma_f32_16x16x32_bf16(a2, b2lo[n], acc2[m][n], 0, 0, 0);
                acc2[m][n] = __builtin_amdgcn_mfma_f32_16x16x32_bf16(a2, b2hi[n], acc2[m][n], 0, 0, 0);
            }
        }
    }

    // ---- layer 3: out = bout + sum_j silu(h2[j]) * Wout[j] (fp32) ----
    float b2v[4], wov[4];
    #pragma unroll
    for (int n = 0; n < 4; ++n) {
        b2v[n] = b2[n * 16 + l15];
        wov[n] = Wout[n * 16 + l15];
    }
    const float bo = bout[0];

    #pragma unroll
    for (int m = 0; m < 2; ++m) {
        float part[4] = {0.f, 0.f, 0.f, 0.f};
        #pragma unroll
        for (int n = 0; n < 4; ++n)
            #pragma unroll
            for (int r = 0; r < 4; ++r)
                part[r] += silu_f(acc2[m][n][r] + b2v[n]) * wov[n];
        #pragma unroll
        for (int mask = 1; mask <= 8; mask <<= 1)
            #pragma unroll
            for (int r = 0; r < 4; ++r)
                part[r] += __shfl_xor(part[r], mask, 64);
        if (l15 == 0) {
            #pragma unroll
            for (int r = 0; r < 4; ++r)
                out[sbase + m * 16 + g * 4 + r] = part[r] + bo;
        }
    }
}

// ---------------- Fallback: monolithic (if ws too small) ----------------
__global__ void __launch_bounds__(BLOCK)
hashgrid_mlp_kernel(const float* __restrict__ x,
                    const float* __restrict__ emb,
                    const float* __restrict__ W1,
                    const float* __restrict__ b1,
                    const float* __restrict__ W2,
                    const float* __restrict__ b2,
                    const float* __restrict__ Wout,
                    const float* __restrict__ bout,
                    float* __restrict__ out,
                    ResArr res)
{
    const int t = threadIdx.x;
    const int s = blockIdx.x * BLOCK + t;

    const float xn0 = (x[(size_t)s * 3 + 0] + 1.0f) * 0.5f;
    const float xn1 = (x[(size_t)s * 3 + 1] + 1.0f) * 0.5f;
    const float xn2 = (x[(size_t)s * 3 + 2] + 1.0f) * 0.5f;

    float enc[2 * NLEV];
    #pragma unroll
    for (int l = 0; l < NLEV; ++l) {
        const float rs = res.r[l];
        const float g0 = xn0 * rs, g1 = xn1 * rs, g2 = xn2 * rs;
        const float f0 = floorf(g0), f1 = floorf(g1), f2 = floorf(g2);
        const float w0 = g0 - f0, w1 = g1 - f1, w2 = g2 - f2;
        const uint32_t hb = (uint32_t)f0 + (uint32_t)f1 * P1 + (uint32_t)f2 * P2;
        const float2* tab = (const float2*)emb + (size_t)l * TBL;
        const float om0 = 1.0f - w0, om1 = 1.0f - w1, om2 = 1.0f - w2;
        float e0 = 0.0f, e1 = 0.0f;
        #pragma unroll
        for (int c = 0; c < 8; ++c) {
            const uint32_t cb0 = (c >> 2) & 1, cb1 = (c >> 1) & 1, cb2 = c & 1;
            uint32_t h = hb;
            if (cb0) h += 1u;
            if (cb1) h += P1;
            if (cb2) h += P2;
            h &= TMASK;
            const float2 vv = tab[h];
            float wt = (cb0 ? w0 : om0) * (cb1 ? w1 : om1);
            wt *= (cb2 ? w2 : om2);
            e0 = fmaf(wt, vv.x, e0);
            e1 = fmaf(wt, vv.y, e1);
        }
        enc[2 * l + 0] = e0;
        enc[2 * l + 1] = e1;
    }

    float h1[64];
    #pragma unroll
    for (int i = 0; i < 64; ++i) {
        float acc = b1[i];
        #pragma unroll
        for (int k = 0; k < 32; ++k)
            acc = fmaf(enc[k], W1[i * 32 + k], acc);
        h1[i] = silu_f(acc);
    }
    float o = bout[0];
    #pragma unroll
    for (int i = 0; i < 64; ++i) {
        float acc = b2[i];
        #pragma unroll
        for (int k = 0; k < 64; ++k)
            acc = fmaf(h1[k], W2[i * 64 + k], acc);
        o = fmaf(silu_f(acc), Wout[i], o);
    }
    out[s] = o;
}

extern "C" void kernel_launch(void* const* d_in, const int* in_sizes, int n_in,
                              void* d_out, int out_size, void* d_ws, size_t ws_size,
                              hipStream_t stream) {
    const float* x    = (const float*)d_in[0];
    const float* emb  = (const float*)d_in[1];
    const float* W1   = (const float*)d_in[2];
    const float* b1   = (const float*)d_in[3];
    const float* W2   = (const float*)d_in[4];
    const float* b2   = (const float*)d_in[5];
    const float* Wout = (const float*)d_in[6];
    const float* bout = (const float*)d_in[7];
    float* out = (float*)d_out;

    ResArr res;
    const double lg0 = log(16.0), lg1 = log(2048.0);
    for (int i = 0; i < NLEV; ++i)
        res.r[i] = (float)exp(lg0 + (lg1 - lg0) * (double)i / 15.0);

    const int n = in_sizes[0] / 3;                     // 262144 samples
    const size_t ws_needed = (size_t)n * NLEV * sizeof(uint32_t);

    if (ws_size >= ws_needed) {
        uint32_t* enc_ws = (uint32_t*)d_ws;
        const int chunks = n / (BLOCK * SPT);          // 256
        dim3 gridA(2 * 8 * chunks);                    // 4096 blocks, phase-split
        encode_kernel<<<gridA, BLOCK, 0, stream>>>(x, emb, enc_ws, n, res);
        dim3 gridB(n / 128);                           // 2048 blocks, 128 samples each
        mlp_mfma_kernel<<<gridB, BLOCK, 0, stream>>>(enc_ws, W1, b1, W2, b2,
                                                     Wout, bout, out, n);
    } else {
        dim3 grid(n / BLOCK);
        hashgrid_mlp_kernel<<<grid, BLOCK, 0, stream>>>(x, emb, W1, b1, W2, b2,
                                                        Wout, bout, out, res);
    }
}

// Round 17
// 129.421 us; speedup vs baseline: 1.2804x; 1.0190x over previous
//
#include <hip/hip_runtime.h>
#include <math.h>
#include <stdint.h>

#define NLEV 16
#define TBL 524288
#define TMASK (TBL - 1)
#define BLOCK 256
#define SPT 4            // samples per thread in encode
#define P1 2654435761u
#define P2 805459861u

struct ResArr { float r[NLEV]; };

typedef __attribute__((ext_vector_type(4))) float f32x4;
typedef __attribute__((ext_vector_type(8))) short bf16x8;   // 8 bf16 = 4 VGPRs
struct __attribute__((packed, aligned(8))) f4wrap { f32x4 v; };

__device__ __forceinline__ float silu_f(float v) {
    return __fdividef(v, 1.0f + __expf(-v));
}

// fp32 -> bf16 bits (RNE)
__device__ __forceinline__ uint32_t f2bf(float f) {
    uint32_t u = __float_as_uint(f);
    return (u + 0x7FFFu + ((u >> 16) & 1u)) >> 16;
}
__device__ __forceinline__ float bf2f(uint32_t b) {
    return __uint_as_float(b << 16);
}
// split x = hi + lo (both bf16) for WEIGHT fragments (B-side keeps precision)
__device__ __forceinline__ void split_bf(float x, bf16x8& hi, bf16x8& lo, int e) {
    const uint32_t hb = f2bf(x);
    hi[e] = (short)hb;
    lo[e] = (short)f2bf(x - bf2f(hb));
}

// ---------------- Kernel A: hash-grid encode ----------------
// Load-BALANCED level->XCD schedule (r16 lesson: per-level cost is bimodal —
// levels 0-4 have sub-L2 footprints ((res+2)^3 entries), levels 5-15 are full
// 4MB random slices; the old {i, i+8} pairing gave XCDs 5-7 TWO full slices
// while XCD 0 had ~1 -> duration = straggler = 2 fulls ~ 99us).
// New schedule: each XCD gets a contiguous 352-block range of the full-level
// blocks (= 1.375 full units, <=3 slices processed SEQUENTIALLY -> one slice
// live in L2 at a time, re-warm cost ~13%) + 160 cheap-level blocks at the
// end. Mapping is arithmetic on blockIdx; any chunk is computed exactly once
// regardless of the blockIdx%8->XCD assumption (perf-only assumption).
__global__ void __launch_bounds__(BLOCK)
encode_kernel(const float* __restrict__ x,
              const float* __restrict__ emb,
              uint32_t* __restrict__ enc_ws,
              int nsamp, ResArr res)
{
    const int bid = blockIdx.x;
    const int xcd = bid & 7;
    const int j   = bid >> 3;                 // per-XCD local index 0..511
    int lvl, chunk;
    if (j < 352) {                            // full levels 5..15 (11 x 256 blocks)
        const int F = xcd * 352 + j;
        lvl = 5 + (F >> 8);
        chunk = F & 255;
    } else {                                  // cheap levels 0..4 (5 x 256 blocks)
        const int C = xcd * 160 + (j - 352);
        lvl = C >> 8;
        chunk = C & 255;
    }

    const int t  = threadIdx.x;
    const int s0 = chunk * (BLOCK * SPT) + t;
    const float rs = res.r[lvl];
    const float* tabf = emb + (size_t)lvl * TBL * 2;

    uint32_t i0[SPT][4];
    float w0[SPT], w1[SPT], w2[SPT];
    uint32_t bad = 0;

    #pragma unroll
    for (int p = 0; p < SPT; ++p) {
        const int s = s0 + p * BLOCK;
        const float xv0 = __builtin_nontemporal_load(&x[(size_t)s * 3 + 0]);
        const float xv1 = __builtin_nontemporal_load(&x[(size_t)s * 3 + 1]);
        const float xv2 = __builtin_nontemporal_load(&x[(size_t)s * 3 + 2]);
        const float g0 = (xv0 + 1.0f) * 0.5f * rs;
        const float g1 = (xv1 + 1.0f) * 0.5f * rs;
        const float g2 = (xv2 + 1.0f) * 0.5f * rs;
        const float f0 = floorf(g0), f1 = floorf(g1), f2 = floorf(g2);
        w0[p] = g0 - f0; w1[p] = g1 - f1; w2[p] = g2 - f2;
        const uint32_t hb = (uint32_t)f0 + (uint32_t)f1 * P1 + (uint32_t)f2 * P2;
        #pragma unroll
        for (int q = 0; q < 4; ++q) {
            uint32_t h = hb;
            if ((q >> 1) & 1) h += P1;
            if (q & 1)        h += P2;
            i0[p][q] = h & TMASK;
            bad |= (uint32_t)(i0[p][q] == TMASK);
        }
    }

    f32x4 v[SPT][4];
    if (__builtin_expect(__any((int)bad), 0)) {
        #pragma unroll
        for (int p = 0; p < SPT; ++p)
            #pragma unroll
            for (int q = 0; q < 4; ++q) {
                const uint32_t a = i0[p][q];
                const uint32_t b = (a + 1u) & TMASK;
                const float2 lo = *(const float2*)(tabf + 2 * (size_t)a);
                const float2 hi = *(const float2*)(tabf + 2 * (size_t)b);
                v[p][q] = f32x4{lo.x, lo.y, hi.x, hi.y};
            }
    } else {
        #pragma unroll
        for (int p = 0; p < SPT; ++p)
            #pragma unroll
            for (int q = 0; q < 4; ++q)
                v[p][q] = ((const f4wrap*)(tabf + 2 * (size_t)i0[p][q]))->v;
    }

    #pragma unroll
    for (int p = 0; p < SPT; ++p) {
        const float om0 = 1.0f - w0[p], om1 = 1.0f - w1[p], om2 = 1.0f - w2[p];
        float e0 = 0.0f, e1 = 0.0f;
        #pragma unroll
        for (int q = 0; q < 4; ++q) {
            float wb = (((q >> 1) & 1) ? w1[p] : om1) * ((q & 1) ? w2[p] : om2);
            const float c0 = om0 * wb;
            const float c1 = w0[p] * wb;
            e0 = fmaf(c0, v[p][q].x, fmaf(c1, v[p][q].z, e0));
            e1 = fmaf(c0, v[p][q].y, fmaf(c1, v[p][q].w, e1));
        }
        const int s = s0 + p * BLOCK;
        const uint32_t pk = f2bf(e0) | (f2bf(e1) << 16);
        __builtin_nontemporal_store(pk, &enc_ws[(size_t)lvl * nsamp + s]);
    }
}

// ---------------- Kernel B: MLP via bf16-A / split-bf16-B MFMA ----------------
// (unchanged from r16: ~30us) A-side plain bf16 (enc pre-converted; h rounded
// once, ~3e-6 output error). B-side weights split hi+lo: 2 MFMAs/product.
// Weight fragments read once per wave, amortized over 16-sample tiles.
// C/D layout (HW-verified): col = lane&15, row = (lane>>4)*4 + reg.
__global__ void __launch_bounds__(BLOCK)
mlp_mfma_kernel(const uint32_t* __restrict__ enc_ws,
                const float* __restrict__ W1,
                const float* __restrict__ b1,
                const float* __restrict__ W2,
                const float* __restrict__ b2,
                const float* __restrict__ Wout,
                const float* __restrict__ bout,
                float* __restrict__ out, int nsamp)
{
    __shared__ __align__(16) unsigned short hbuf[4][32 * 72];

    const int tid  = threadIdx.x;
    const int wid  = tid >> 6;
    const int lane = tid & 63;
    const int l15  = lane & 15;
    const int g    = lane >> 4;
    const int sbase = blockIdx.x * 128 + wid * 32;
    unsigned short* hw = hbuf[wid];

    bf16x8 b1hi[4], b1lo[4];
    float  b1v[4];
    #pragma unroll
    for (int n = 0; n < 4; ++n) {
        const float* wr = W1 + (n * 16 + l15) * 32 + g * 8;
        const f32x4 wv0 = ((const f4wrap*)wr)->v;
        const f32x4 wv1 = ((const f4wrap*)(wr + 4))->v;
        #pragma unroll
        for (int e = 0; e < 4; ++e) {
            split_bf(wv0[e], b1hi[n], b1lo[n], e);
            split_bf(wv1[e], b1hi[n], b1lo[n], e + 4);
        }
        b1v[n] = b1[n * 16 + l15];
    }

    #pragma unroll
    for (int m = 0; m < 2; ++m) {
        union { uint32_t u[4]; bf16x8 v; } af;
        const int s = sbase + m * 16 + l15;
        #pragma unroll
        for (int d = 0; d < 4; ++d)
            af.u[d] = enc_ws[(size_t)(g * 4 + d) * nsamp + s];
        #pragma unroll
        for (int n = 0; n < 4; ++n) {
            f32x4 acc = {0.f, 0.f, 0.f, 0.f};
            acc = __builtin_amdgcn_mfma_f32_16x16x32_bf16(af.v, b1lo[n], acc, 0, 0, 0);
            acc = __builtin_amdgcn_mfma_f32_16x16x32_bf16(af.v, b1hi[n], acc, 0, 0, 0);
            #pragma unroll
            for (int r = 0; r < 4; ++r) {
                const int row = m * 16 + g * 4 + r;
                const int col = n * 16 + l15;
                hw[row * 72 + col] = (unsigned short)f2bf(silu_f(acc[r] + b1v[n]));
            }
        }
    }

    f32x4 acc2[2][4];
    #pragma unroll
    for (int m = 0; m < 2; ++m)
        #pragma unroll
        for (int n = 0; n < 4; ++n)
            acc2[m][n] = f32x4{0.f, 0.f, 0.f, 0.f};

    #pragma unroll
    for (int ks = 0; ks < 2; ++ks) {
        bf16x8 b2hi[4], b2lo[4];
        #pragma unroll
        for (int n = 0; n < 4; ++n) {
            const float* wr = W2 + (n * 16 + l15) * 64 + ks * 32 + g * 8;
            const f32x4 wv0 = ((const f4wrap*)wr)->v;
            const f32x4 wv1 = ((const f4wrap*)(wr + 4))->v;
            #pragma unroll
            for (int e = 0; e < 4; ++e) {
                split_bf(wv0[e], b2hi[n], b2lo[n], e);
                split_bf(wv1[e], b2hi[n], b2lo[n], e + 4);
            }
        }
        #pragma unroll
        for (int m = 0; m < 2; ++m) {
            const bf16x8 a2 = *(const bf16x8*)&hw[(m * 16 + l15) * 72 + ks * 32 + g * 8];
            #pragma unroll
            for (int n = 0; n < 4; ++n) {
                acc2[m][n] = __builtin_amdgcn_mfma_f32_16x16x32_bf16(a2, b2lo[n], acc2[m][n], 0, 0, 0);
                acc2[m][n] = __builtin_amdgcn_mfma_f32_16x16x32_bf16(a2, b2hi[n], acc2[m][n], 0, 0, 0);
            }
        }
    }

    float b2v[4], wov[4];
    #pragma unroll
    for (int n = 0; n < 4; ++n) {
        b2v[n] = b2[n * 16 + l15];
        wov[n] = Wout[n * 16 + l15];
    }
    const float bo = bout[0];

    #pragma unroll
    for (int m = 0; m < 2; ++m) {
        float part[4] = {0.f, 0.f, 0.f, 0.f};
        #pragma unroll
        for (int n = 0; n < 4; ++n)
            #pragma unroll
            for (int r = 0; r < 4; ++r)
                part[r] += silu_f(acc2[m][n][r] + b2v[n]) * wov[n];
        #pragma unroll
        for (int mask = 1; mask <= 8; mask <<= 1)
            #pragma unroll
            for (int r = 0; r < 4; ++r)
                part[r] += __shfl_xor(part[r], mask, 64);
        if (l15 == 0) {
            #pragma unroll
            for (int r = 0; r < 4; ++r)
                out[sbase + m * 16 + g * 4 + r] = part[r] + bo;
        }
    }
}

// ---------------- Fallback: monolithic (if ws too small) ----------------
__global__ void __launch_bounds__(BLOCK)
hashgrid_mlp_kernel(const float* __restrict__ x,
                    const float* __restrict__ emb,
                    const float* __restrict__ W1,
                    const float* __restrict__ b1,
                    const float* __restrict__ W2,
                    const float* __restrict__ b2,
                    const float* __restrict__ Wout,
                    const float* __restrict__ bout,
                    float* __restrict__ out,
                    ResArr res)
{
    const int t = threadIdx.x;
    const int s = blockIdx.x * BLOCK + t;

    const float xn0 = (x[(size_t)s * 3 + 0] + 1.0f) * 0.5f;
    const float xn1 = (x[(size_t)s * 3 + 1] + 1.0f) * 0.5f;
    const float xn2 = (x[(size_t)s * 3 + 2] + 1.0f) * 0.5f;

    float enc[2 * NLEV];
    #pragma unroll
    for (int l = 0; l < NLEV; ++l) {
        const float rs = res.r[l];
        const float g0 = xn0 * rs, g1 = xn1 * rs, g2 = xn2 * rs;
        const float f0 = floorf(g0), f1 = floorf(g1), f2 = floorf(g2);
        const float w0 = g0 - f0, w1 = g1 - f1, w2 = g2 - f2;
        const uint32_t hb = (uint32_t)f0 + (uint32_t)f1 * P1 + (uint32_t)f2 * P2;
        const float2* tab = (const float2*)emb + (size_t)l * TBL;
        const float om0 = 1.0f - w0, om1 = 1.0f - w1, om2 = 1.0f - w2;
        float e0 = 0.0f, e1 = 0.0f;
        #pragma unroll
        for (int c = 0; c < 8; ++c) {
            const uint32_t cb0 = (c >> 2) & 1, cb1 = (c >> 1) & 1, cb2 = c & 1;
            uint32_t h = hb;
            if (cb0) h += 1u;
            if (cb1) h += P1;
            if (cb2) h += P2;
            h &= TMASK;
            const float2 vv = tab[h];
            float wt = (cb0 ? w0 : om0) * (cb1 ? w1 : om1);
            wt *= (cb2 ? w2 : om2);
            e0 = fmaf(wt, vv.x, e0);
            e1 = fmaf(wt, vv.y, e1);
        }
        enc[2 * l + 0] = e0;
        enc[2 * l + 1] = e1;
    }

    float h1[64];
    #pragma unroll
    for (int i = 0; i < 64; ++i) {
        float acc = b1[i];
        #pragma unroll
        for (int k = 0; k < 32; ++k)
            acc = fmaf(enc[k], W1[i * 32 + k], acc);
        h1[i] = silu_f(acc);
    }
    float o = bout[0];
    #pragma unroll
    for (int i = 0; i < 64; ++i) {
        float acc = b2[i];
        #pragma unroll
        for (int k = 0; k < 64; ++k)
            acc = fmaf(h1[k], W2[i * 64 + k], acc);
        o = fmaf(silu_f(acc), Wout[i], o);
    }
    out[s] = o;
}

extern "C" void kernel_launch(void* const* d_in, const int* in_sizes, int n_in,
                              void* d_out, int out_size, void* d_ws, size_t ws_size,
                              hipStream_t stream) {
    const float* x    = (const float*)d_in[0];
    const float* emb  = (const float*)d_in[1];
    const float* W1   = (const float*)d_in[2];
    const float* b1   = (const float*)d_in[3];
    const float* W2   = (const float*)d_in[4];
    const float* b2   = (const float*)d_in[5];
    const float* Wout = (const float*)d_in[6];
    const float* bout = (const float*)d_in[7];
    float* out = (float*)d_out;

    ResArr res;
    const double lg0 = log(16.0), lg1 = log(2048.0);
    for (int i = 0; i < NLEV; ++i)
        res.r[i] = (float)exp(lg0 + (lg1 - lg0) * (double)i / 15.0);

    const int n = in_sizes[0] / 3;                     // 262144 samples
    const size_t ws_needed = (size_t)n * NLEV * sizeof(uint32_t);

    if (ws_size >= ws_needed) {
        uint32_t* enc_ws = (uint32_t*)d_ws;
        dim3 gridA(4096);                              // 512 blocks per XCD, balanced
        encode_kernel<<<gridA, BLOCK, 0, stream>>>(x, emb, enc_ws, n, res);
        dim3 gridB(n / 128);                           // 2048 blocks, 128 samples each
        mlp_mfma_kernel<<<gridB, BLOCK, 0, stream>>>(enc_ws, W1, b1, W2, b2,
                                                     Wout, bout, out, n);
    } else {
        dim3 grid(n / BLOCK);
        hashgrid_mlp_kernel<<<grid, BLOCK, 0, stream>>>(x, emb, W1, b1, W2, b2,
                                                        Wout, bout, out, res);
    }
}